// Round 4
// baseline (1291.157 us; speedup 1.0000x reference)
//
#include <hip/hip_runtime.h>
#include <hip/hip_bf16.h>

// Problem constants (fixed by the reference)
constexpr int NN   = 50000;     // nodes
constexpr int NE   = 1600000;   // directed edges (self-loops handled analytically)
constexpr int CIN  = 512;
constexpr int DH   = 64;        // H1*F1 = 64 = C_OUT
constexpr int H1N  = 8;

__device__ __forceinline__ float bf(unsigned short u) {
    union { unsigned int i; float f; } v; v.i = ((unsigned int)u) << 16; return v.f;
}
__device__ __forceinline__ float bflo(unsigned int u) {
    union { unsigned int i; float f; } v; v.i = u << 16; return v.f;
}
__device__ __forceinline__ float bfhi(unsigned int u) {
    union { unsigned int i; float f; } v; v.i = u & 0xffff0000u; return v.f;
}
__device__ __forceinline__ float lrelu(float x) { return x > 0.f ? x : 0.2f * x; }
// dtype-adaptive scalar load of a "float tensor" that may be fp32 or bf16
__device__ __forceinline__ float ldf(const unsigned short* p, size_t i, bool f32) {
    return f32 ? ((const float*)p)[i] : bf(p[i]);
}

// ---------------- dtype detector ----------------
// Glorot W1: |w| <= 0.102 -> every bf16 halfword has biased exponent <= 123.
// If the buffer is fp32, the LOW halfword of each float is ~uniform random
// -> ~45% of them have exponent >= 140. Count and decide.
__global__ __launch_bounds__(256) void gat_detect(const unsigned short* __restrict__ W1,
                                                  int* __restrict__ flag) {
    __shared__ int cnt;
    if (threadIdx.x == 0) cnt = 0;
    __syncthreads();
    int local = 0;
    for (int i = threadIdx.x; i < 4096; i += 256) {
        unsigned short u = W1[i];
        int e = (u >> 7) & 0xFF;
        if (e >= 140) local++;
    }
    atomicAdd(&cnt, local);
    __syncthreads();
    if (threadIdx.x == 0) flag[0] = (cnt > 100) ? 1 : 0;   // 1 = fp32 buffers
}

// ---------------- CSR construction ----------------

__global__ __launch_bounds__(256) void gat_degree(const int* __restrict__ dst,
                                                  int* __restrict__ counts) {
    int e = blockIdx.x * 256 + threadIdx.x;
    if (e < NE) atomicAdd(&counts[dst[e]], 1);
}

__global__ __launch_bounds__(256) void gat_scan(const int* __restrict__ counts,
                                                int* __restrict__ row_ptr,
                                                int* __restrict__ cursor) {
    __shared__ int sums[256];
    int t = threadIdx.x;
    const int CH = (NN + 255) / 256;          // 196
    int base = t * CH;
    int cnt = NN - base; if (cnt > CH) cnt = CH; if (cnt < 0) cnt = 0;
    int s = 0;
    for (int i = 0; i < cnt; ++i) s += counts[base + i];
    sums[t] = s;
    __syncthreads();
    for (int off = 1; off < 256; off <<= 1) {
        int v = sums[t];
        int add = (t >= off) ? sums[t - off] : 0;
        __syncthreads();
        sums[t] = v + add;
        __syncthreads();
    }
    int run = (t == 0) ? 0 : sums[t - 1];
    for (int i = 0; i < cnt; ++i) {
        row_ptr[base + i] = run;
        cursor[base + i]  = run;
        run += counts[base + i];
    }
    if (t == 255) row_ptr[NN] = sums[255];
}

__global__ __launch_bounds__(256) void gat_scatter(const int* __restrict__ src,
                                                   const int* __restrict__ dst,
                                                   int* __restrict__ cursor,
                                                   int* __restrict__ col_idx) {
    int e = blockIdx.x * 256 + threadIdx.x;
    if (e < NE) {
        int d = dst[e];
        int p = atomicAdd(&cursor[d], 1);
        col_idx[p] = src[e];
    }
}

// ---------------- Layer 1 GEMM: h1 = x @ W1 (k-half per launch) ----------------
// W1 k-half staged as fp32 in 64 KiB LDS. One wave processes 4 rows; lane=col.
// final_phase: add partial from phase 0, write final h1, compute a_s1/a_d1.

__global__ __launch_bounds__(256) void gat_gemm1(const unsigned short* __restrict__ xr,
                                                 const unsigned short* __restrict__ W1,
                                                 const unsigned short* __restrict__ as1,
                                                 const unsigned short* __restrict__ ad1,
                                                 const int* __restrict__ flag,
                                                 float* __restrict__ h1,
                                                 float* __restrict__ a_s1,
                                                 float* __restrict__ a_d1,
                                                 int kbase, int final_phase) {
    __shared__ float wh[256 * DH];   // 64 KiB
    const bool f32 = (flag[0] != 0);
    int t = threadIdx.x;
    for (int idx = t; idx < 256 * DH; idx += 256) {
        int kk = idx >> 6, c = idx & 63;
        wh[idx] = ldf(W1, (size_t)(kbase + kk) * DH + c, f32);
    }
    __syncthreads();

    int lane = t & 63, wv = t >> 6;
    float asv = 0.f, adv = 0.f;
    if (final_phase) {
        asv = ldf(as1, lane, f32);
        adv = ldf(ad1, lane, f32);
    }

    int stride = gridDim.x * 16;
    for (int r0 = (blockIdx.x * 4 + wv) * 4; r0 < NN; r0 += stride) {
        float acc[4];
#pragma unroll
        for (int r = 0; r < 4; ++r)
            acc[r] = final_phase ? h1[(size_t)(r0 + r) * DH + lane] : 0.f;

        for (int k = 0; k < 256; k += 4) {
            float xs[4][4];
            if (f32) {
                const float* xf = (const float*)xr;
#pragma unroll
                for (int r = 0; r < 4; ++r) {
                    float4 v = *(const float4*)(xf + (size_t)(r0 + r) * CIN + kbase + k);
                    xs[r][0] = v.x; xs[r][1] = v.y; xs[r][2] = v.z; xs[r][3] = v.w;
                }
            } else {
#pragma unroll
                for (int r = 0; r < 4; ++r) {
                    uint2 u = *(const uint2*)(xr + (size_t)(r0 + r) * CIN + kbase + k);
                    xs[r][0] = bflo(u.x); xs[r][1] = bfhi(u.x);
                    xs[r][2] = bflo(u.y); xs[r][3] = bfhi(u.y);
                }
            }
#pragma unroll
            for (int kk = 0; kk < 4; ++kk) {
                float w = wh[(k + kk) * DH + lane];
#pragma unroll
                for (int r = 0; r < 4; ++r) acc[r] += xs[r][kk] * w;
            }
        }

#pragma unroll
        for (int r = 0; r < 4; ++r) {
            int row = r0 + r;
            h1[(size_t)row * DH + lane] = acc[r];
            if (final_phase) {
                float ps = acc[r] * asv, pd = acc[r] * adv;
#pragma unroll
                for (int o = 1; o < 8; o <<= 1) {
                    ps += __shfl_xor(ps, o, 64);
                    pd += __shfl_xor(pd, o, 64);
                }
                if ((lane & 7) == 0) {
                    int h = lane >> 3;
                    a_s1[row * H1N + h] = ps;
                    a_d1[row * H1N + h] = pd;
                }
            }
        }
    }
}

// ---------------- Layer 1 aggregation (stable softmax) + bias + ELU ----------------

__global__ __launch_bounds__(256) void gat_agg1(const int* __restrict__ row_ptr,
                                                const int* __restrict__ col_idx,
                                                const float* __restrict__ a_s1,
                                                const float* __restrict__ a_d1,
                                                const float* __restrict__ h1,
                                                const unsigned short* __restrict__ b1,
                                                const int* __restrict__ flag,
                                                float* __restrict__ hout) {
    const bool f32 = (flag[0] != 0);
    int i = (blockIdx.x * 256 + threadIdx.x) >> 6;
    int lane = threadIdx.x & 63;
    if (i >= NN) return;
    int h = lane >> 3;

    float adst = a_d1[i * H1N + h];
    float eself = lrelu(a_s1[i * H1N + h] + adst);
    int jb = row_ptr[i], je = row_ptr[i + 1];

    // pass 1: segment max (self-loop included)
    float m = eself;
    for (int j = jb; j < je; ++j) {
        int s = col_idx[j];
        m = fmaxf(m, lrelu(a_s1[s * H1N + h] + adst));
    }
    // pass 2: exp(e - m), accumulate
    float w = __expf(eself - m);
    float denom = w;
    float acc = w * h1[(size_t)i * DH + lane];
    for (int j = jb; j < je; ++j) {
        int s = col_idx[j];
        float ww = __expf(lrelu(a_s1[s * H1N + h] + adst) - m);
        denom += ww;
        acc += ww * h1[(size_t)s * DH + lane];
    }
    float val = acc / denom + ldf(b1, lane, f32);
    val = val > 0.f ? val : 0.2f * (__expf(val) - 1.f);   // ELU alpha=0.2
    hout[(size_t)i * DH + lane] = val;
}

// ---------------- Layer 2 GEMM: h2 = h @ W2, + a_src2/a_dst2 (H2=1) ----------------

__global__ __launch_bounds__(256) void gat_gemm2(const float* __restrict__ hin,
                                                 const unsigned short* __restrict__ W2,
                                                 const unsigned short* __restrict__ as2,
                                                 const unsigned short* __restrict__ ad2,
                                                 const int* __restrict__ flag,
                                                 float* __restrict__ h2,
                                                 float* __restrict__ a_s2,
                                                 float* __restrict__ a_d2) {
    __shared__ float w2[DH * DH];   // 16 KiB
    const bool f32 = (flag[0] != 0);
    int t = threadIdx.x;
    int lane = t & 63, wv = t >> 6;
    for (int idx = t; idx < DH * DH; idx += 256) w2[idx] = ldf(W2, idx, f32);
    __syncthreads();

    float asv = ldf(as2, lane, f32);
    float adv = ldf(ad2, lane, f32);

    int stride = gridDim.x * 4;
    for (int row = blockIdx.x * 4 + wv; row < NN; row += stride) {
        const float* hr = hin + (size_t)row * DH;
        float acc = 0.f;
#pragma unroll 8
        for (int k = 0; k < DH; ++k) acc += hr[k] * w2[k * DH + lane];
        h2[(size_t)row * DH + lane] = acc;
        float ps = acc * asv, pd = acc * adv;
#pragma unroll
        for (int o = 1; o < 64; o <<= 1) {
            ps += __shfl_xor(ps, o, 64);
            pd += __shfl_xor(pd, o, 64);
        }
        if (lane == 0) { a_s2[row] = ps; a_d2[row] = pd; }
    }
}

// ---------------- Layer 2 aggregation (stable softmax) + bias ----------------
// Output dtype follows the detected input dtype (fp32 vs bf16).

__global__ __launch_bounds__(256) void gat_agg2(const int* __restrict__ row_ptr,
                                                const int* __restrict__ col_idx,
                                                const float* __restrict__ a_s2,
                                                const float* __restrict__ a_d2,
                                                const float* __restrict__ h2,
                                                const unsigned short* __restrict__ b2,
                                                const int* __restrict__ flag,
                                                void* __restrict__ out) {
    const bool f32 = (flag[0] != 0);
    int i = (blockIdx.x * 256 + threadIdx.x) >> 6;
    int lane = threadIdx.x & 63;
    if (i >= NN) return;

    float adst = a_d2[i];
    float eself = lrelu(a_s2[i] + adst);
    int jb = row_ptr[i], je = row_ptr[i + 1];

    float m = eself;
    for (int j = jb; j < je; ++j) {
        int s = col_idx[j];
        m = fmaxf(m, lrelu(a_s2[s] + adst));
    }
    float w = __expf(eself - m);
    float denom = w;
    float acc = w * h2[(size_t)i * DH + lane];
    for (int j = jb; j < je; ++j) {
        int s = col_idx[j];
        float ww = __expf(lrelu(a_s2[s] + adst) - m);
        denom += ww;
        acc += ww * h2[(size_t)s * DH + lane];
    }
    float val = acc / denom + ldf(b2, lane, f32);
    size_t oi = (size_t)i * DH + lane;
    if (f32) ((float*)out)[oi] = val;
    else     ((__hip_bfloat16*)out)[oi] = __float2bfloat16(val);
}

// ---------------- launch ----------------

static void* g_scratch = nullptr;   // fallback only; allocated on first (non-captured) call

extern "C" void kernel_launch(void* const* d_in, const int* in_sizes, int n_in,
                              void* d_out, int out_size, void* d_ws, size_t ws_size,
                              hipStream_t stream) {
    const unsigned short* x   = (const unsigned short*)d_in[0];
    const int*            ei  = (const int*)d_in[1];
    const unsigned short* W1  = (const unsigned short*)d_in[2];
    const unsigned short* as1 = (const unsigned short*)d_in[3];
    const unsigned short* ad1 = (const unsigned short*)d_in[4];
    const unsigned short* b1  = (const unsigned short*)d_in[5];
    const unsigned short* W2  = (const unsigned short*)d_in[6];
    const unsigned short* as2 = (const unsigned short*)d_in[7];
    const unsigned short* ad2 = (const unsigned short*)d_in[8];
    const unsigned short* b2  = (const unsigned short*)d_in[9];

    const int* srcv = ei;
    const int* dstv = ei + NE;

    // ws carve: flag(16) + h1/h2 + hmid + a_s1 + a_d1 + counts + row_ptr + cursor + col_idx
    const size_t need = (16 + (size_t)NN * DH * 2 + (size_t)NN * H1N * 2
                         + (size_t)NN * 3 + 1 + (size_t)NE) * 4;
    void* wsbase = d_ws;
    if (ws_size < need) {
        if (g_scratch == nullptr) hipMalloc(&g_scratch, need);
        wsbase = g_scratch;
    }

    int*   flag = (int*)wsbase;              // 16 ints
    float* h1   = (float*)wsbase + 16;       // NN*64 (reused as h2)
    float* hmid = h1   + (size_t)NN * DH;    // NN*64
    float* a_s1 = hmid + (size_t)NN * DH;    // NN*8
    float* a_d1 = a_s1 + (size_t)NN * H1N;   // NN*8
    int* counts  = (int*)(a_d1 + (size_t)NN * H1N);  // NN
    int* row_ptr = counts  + NN;             // NN+1
    int* cursor  = row_ptr + (NN + 1);       // NN
    int* col_idx = cursor  + NN;             // NE
    float* h2   = h1;                        // alias: h1 dead after agg1
    float* a_s2 = a_s1;                      // alias
    float* a_d2 = a_d1;                      // alias

    hipMemsetAsync(counts, 0, NN * sizeof(int), stream);
    gat_detect<<<1, 256, 0, stream>>>(W1, flag);

    int eb = (NE + 255) / 256;
    gat_degree <<<eb, 256, 0, stream>>>(dstv, counts);
    gat_scan   <<<1, 256, 0, stream>>>(counts, row_ptr, cursor);
    gat_scatter<<<eb, 256, 0, stream>>>(srcv, dstv, cursor, col_idx);

    gat_gemm1<<<1024, 256, 0, stream>>>(x, W1, as1, ad1, flag, h1, a_s1, a_d1, 0, 0);
    gat_gemm1<<<1024, 256, 0, stream>>>(x, W1, as1, ad1, flag, h1, a_s1, a_d1, 256, 1);

    int nb = (NN * 64 + 255) / 256;   // one wave per node
    gat_agg1<<<nb, 256, 0, stream>>>(row_ptr, col_idx, a_s1, a_d1, h1, b1, flag, hmid);

    gat_gemm2<<<512, 256, 0, stream>>>(hmid, W2, as2, ad2, flag, h2, a_s2, a_d2);

    gat_agg2<<<nb, 256, 0, stream>>>(row_ptr, col_idx, a_s2, a_d2, h2, b2, flag, d_out);
}

// Round 5
// 1075.254 us; speedup vs baseline: 1.2008x; 1.2008x over previous
//
#include <hip/hip_runtime.h>
#include <hip/hip_bf16.h>

// Problem constants (fixed by the reference)
constexpr int NN   = 50000;     // nodes
constexpr int NE   = 1600000;   // directed edges (self-loops handled analytically)
constexpr int CIN  = 512;
constexpr int DH   = 64;        // H1*F1 = 64 = C_OUT
constexpr int H1N  = 8;

__device__ __forceinline__ float bf(unsigned short u) {
    union { unsigned int i; float f; } v; v.i = ((unsigned int)u) << 16; return v.f;
}
__device__ __forceinline__ float bflo(unsigned int u) {
    union { unsigned int i; float f; } v; v.i = u << 16; return v.f;
}
__device__ __forceinline__ float bfhi(unsigned int u) {
    union { unsigned int i; float f; } v; v.i = u & 0xffff0000u; return v.f;
}
__device__ __forceinline__ float lrelu(float x) { return x > 0.f ? x : 0.2f * x; }
// dtype-adaptive scalar load of a "float tensor" that may be fp32 or bf16
__device__ __forceinline__ float ldf(const unsigned short* p, size_t i, bool f32) {
    return f32 ? ((const float*)p)[i] : bf(p[i]);
}

// ---------------- dtype detector (unchanged from passing round) ----------------
__global__ __launch_bounds__(256) void gat_detect(const unsigned short* __restrict__ W1,
                                                  int* __restrict__ flag) {
    __shared__ int cnt;
    if (threadIdx.x == 0) cnt = 0;
    __syncthreads();
    int local = 0;
    for (int i = threadIdx.x; i < 4096; i += 256) {
        unsigned short u = W1[i];
        int e = (u >> 7) & 0xFF;
        if (e >= 140) local++;
    }
    atomicAdd(&cnt, local);
    __syncthreads();
    if (threadIdx.x == 0) flag[0] = (cnt > 100) ? 1 : 0;   // 1 = fp32 buffers
}

// ---------------- CSR construction (unchanged) ----------------

__global__ __launch_bounds__(256) void gat_degree(const int* __restrict__ dst,
                                                  int* __restrict__ counts) {
    int e = blockIdx.x * 256 + threadIdx.x;
    if (e < NE) atomicAdd(&counts[dst[e]], 1);
}

__global__ __launch_bounds__(256) void gat_scan(const int* __restrict__ counts,
                                                int* __restrict__ row_ptr,
                                                int* __restrict__ cursor) {
    __shared__ int sums[256];
    int t = threadIdx.x;
    const int CH = (NN + 255) / 256;          // 196
    int base = t * CH;
    int cnt = NN - base; if (cnt > CH) cnt = CH; if (cnt < 0) cnt = 0;
    int s = 0;
    for (int i = 0; i < cnt; ++i) s += counts[base + i];
    sums[t] = s;
    __syncthreads();
    for (int off = 1; off < 256; off <<= 1) {
        int v = sums[t];
        int add = (t >= off) ? sums[t - off] : 0;
        __syncthreads();
        sums[t] = v + add;
        __syncthreads();
    }
    int run = (t == 0) ? 0 : sums[t - 1];
    for (int i = 0; i < cnt; ++i) {
        row_ptr[base + i] = run;
        cursor[base + i]  = run;
        run += counts[base + i];
    }
    if (t == 255) row_ptr[NN] = sums[255];
}

__global__ __launch_bounds__(256) void gat_scatter(const int* __restrict__ src,
                                                   const int* __restrict__ dst,
                                                   int* __restrict__ cursor,
                                                   int* __restrict__ col_idx) {
    int e = blockIdx.x * 256 + threadIdx.x;
    if (e < NE) {
        int d = dst[e];
        int p = atomicAdd(&cursor[d], 1);
        col_idx[p] = src[e];
    }
}

// ---------------- Layer 1 GEMM (unchanged) ----------------

__global__ __launch_bounds__(256) void gat_gemm1(const unsigned short* __restrict__ xr,
                                                 const unsigned short* __restrict__ W1,
                                                 const unsigned short* __restrict__ as1,
                                                 const unsigned short* __restrict__ ad1,
                                                 const int* __restrict__ flag,
                                                 float* __restrict__ h1,
                                                 float* __restrict__ a_s1,
                                                 float* __restrict__ a_d1,
                                                 int kbase, int final_phase) {
    __shared__ float wh[256 * DH];   // 64 KiB
    const bool f32 = (flag[0] != 0);
    int t = threadIdx.x;
    for (int idx = t; idx < 256 * DH; idx += 256) {
        int kk = idx >> 6, c = idx & 63;
        wh[idx] = ldf(W1, (size_t)(kbase + kk) * DH + c, f32);
    }
    __syncthreads();

    int lane = t & 63, wv = t >> 6;
    float asv = 0.f, adv = 0.f;
    if (final_phase) {
        asv = ldf(as1, lane, f32);
        adv = ldf(ad1, lane, f32);
    }

    int stride = gridDim.x * 16;
    for (int r0 = (blockIdx.x * 4 + wv) * 4; r0 < NN; r0 += stride) {
        float acc[4];
#pragma unroll
        for (int r = 0; r < 4; ++r)
            acc[r] = final_phase ? h1[(size_t)(r0 + r) * DH + lane] : 0.f;

        for (int k = 0; k < 256; k += 4) {
            float xs[4][4];
            if (f32) {
                const float* xf = (const float*)xr;
#pragma unroll
                for (int r = 0; r < 4; ++r) {
                    float4 v = *(const float4*)(xf + (size_t)(r0 + r) * CIN + kbase + k);
                    xs[r][0] = v.x; xs[r][1] = v.y; xs[r][2] = v.z; xs[r][3] = v.w;
                }
            } else {
#pragma unroll
                for (int r = 0; r < 4; ++r) {
                    uint2 u = *(const uint2*)(xr + (size_t)(r0 + r) * CIN + kbase + k);
                    xs[r][0] = bflo(u.x); xs[r][1] = bfhi(u.x);
                    xs[r][2] = bflo(u.y); xs[r][3] = bfhi(u.y);
                }
            }
#pragma unroll
            for (int kk = 0; kk < 4; ++kk) {
                float w = wh[(k + kk) * DH + lane];
#pragma unroll
                for (int r = 0; r < 4; ++r) acc[r] += xs[r][kk] * w;
            }
        }

#pragma unroll
        for (int r = 0; r < 4; ++r) {
            int row = r0 + r;
            h1[(size_t)row * DH + lane] = acc[r];
            if (final_phase) {
                float ps = acc[r] * asv, pd = acc[r] * adv;
#pragma unroll
                for (int o = 1; o < 8; o <<= 1) {
                    ps += __shfl_xor(ps, o, 64);
                    pd += __shfl_xor(pd, o, 64);
                }
                if ((lane & 7) == 0) {
                    int h = lane >> 3;
                    a_s1[row * H1N + h] = ps;
                    a_d1[row * H1N + h] = pd;
                }
            }
        }
    }
}

// ---------------- Layer 1 aggregation: single-pass online softmax, batch-4 ----------------
// One wave per destination node; lane = h*8+f. Self-loop is the init state
// (m = e_self, denom = 1, acc = h_self). Batch of 4 edges per iteration gives
// 4 independent a_s1 gathers + 4 independent h1-row gathers in flight.

__global__ __launch_bounds__(256) void gat_agg1(const int* __restrict__ row_ptr,
                                                const int* __restrict__ col_idx,
                                                const float* __restrict__ a_s1,
                                                const float* __restrict__ a_d1,
                                                const float* __restrict__ h1,
                                                const unsigned short* __restrict__ b1,
                                                const int* __restrict__ flag,
                                                float* __restrict__ hout) {
    const bool f32 = (flag[0] != 0);
    int i = (blockIdx.x * 256 + threadIdx.x) >> 6;
    int lane = threadIdx.x & 63;
    if (i >= NN) return;
    int h = lane >> 3;

    float adst = a_d1[i * H1N + h];
    int jb = row_ptr[i], je = row_ptr[i + 1];
    int deg = je - jb;

    // lane L caches col_idx[jb+L]; covers deg<=64 without further pointer loads
    int myidx = (lane < deg) ? col_idx[jb + lane] : 0;

    // online-softmax state, initialized with the self-loop edge
    float m = lrelu(a_s1[i * H1N + h] + adst);
    float denom = 1.f;
    float acc = h1[(size_t)i * DH + lane];

    for (int j0 = 0; j0 < deg; j0 += 4) {
        int   s[4]; float e[4];
#pragma unroll
        for (int k = 0; k < 4; ++k) {
            int jj = j0 + k;
            int jv = (jj < deg) ? jj : j0;            // clamp tail to a valid edge
            s[k] = (jv < 64) ? __shfl(myidx, jv, 64) : col_idx[jb + jv];
            e[k] = (jj < deg) ? lrelu(a_s1[s[k] * H1N + h] + adst) : -1e30f;
        }
        float r[4];
#pragma unroll
        for (int k = 0; k < 4; ++k) r[k] = h1[(size_t)s[k] * DH + lane];

        float bm = fmaxf(fmaxf(e[0], e[1]), fmaxf(e[2], e[3]));
        float mn = fmaxf(m, bm);
        float sc = __expf(m - mn);
        float w0 = __expf(e[0] - mn), w1 = __expf(e[1] - mn);
        float w2 = __expf(e[2] - mn), w3 = __expf(e[3] - mn);
        denom = denom * sc + ((w0 + w1) + (w2 + w3));
        acc   = acc   * sc + (w0 * r[0] + w1 * r[1]) + (w2 * r[2] + w3 * r[3]);
        m = mn;
    }

    float val = acc / denom + ldf(b1, lane, f32);
    val = val > 0.f ? val : 0.2f * (__expf(val) - 1.f);   // ELU alpha=0.2
    hout[(size_t)i * DH + lane] = val;
}

// ---------------- Layer 2 GEMM (unchanged) ----------------

__global__ __launch_bounds__(256) void gat_gemm2(const float* __restrict__ hin,
                                                 const unsigned short* __restrict__ W2,
                                                 const unsigned short* __restrict__ as2,
                                                 const unsigned short* __restrict__ ad2,
                                                 const int* __restrict__ flag,
                                                 float* __restrict__ h2,
                                                 float* __restrict__ a_s2,
                                                 float* __restrict__ a_d2) {
    __shared__ float w2[DH * DH];   // 16 KiB
    const bool f32 = (flag[0] != 0);
    int t = threadIdx.x;
    int lane = t & 63, wv = t >> 6;
    for (int idx = t; idx < DH * DH; idx += 256) w2[idx] = ldf(W2, idx, f32);
    __syncthreads();

    float asv = ldf(as2, lane, f32);
    float adv = ldf(ad2, lane, f32);

    int stride = gridDim.x * 4;
    for (int row = blockIdx.x * 4 + wv; row < NN; row += stride) {
        const float* hr = hin + (size_t)row * DH;
        float acc = 0.f;
#pragma unroll 8
        for (int k = 0; k < DH; ++k) acc += hr[k] * w2[k * DH + lane];
        h2[(size_t)row * DH + lane] = acc;
        float ps = acc * asv, pd = acc * adv;
#pragma unroll
        for (int o = 1; o < 64; o <<= 1) {
            ps += __shfl_xor(ps, o, 64);
            pd += __shfl_xor(pd, o, 64);
        }
        if (lane == 0) { a_s2[row] = ps; a_d2[row] = pd; }
    }
}

// ---------------- Layer 2 aggregation: single-pass online softmax, batch-4 ----------------

__global__ __launch_bounds__(256) void gat_agg2(const int* __restrict__ row_ptr,
                                                const int* __restrict__ col_idx,
                                                const float* __restrict__ a_s2,
                                                const float* __restrict__ a_d2,
                                                const float* __restrict__ h2,
                                                const unsigned short* __restrict__ b2,
                                                const int* __restrict__ flag,
                                                void* __restrict__ out) {
    const bool f32 = (flag[0] != 0);
    int i = (blockIdx.x * 256 + threadIdx.x) >> 6;
    int lane = threadIdx.x & 63;
    if (i >= NN) return;

    float adst = a_d2[i];
    int jb = row_ptr[i], je = row_ptr[i + 1];
    int deg = je - jb;

    int myidx = (lane < deg) ? col_idx[jb + lane] : 0;

    float m = lrelu(a_s2[i] + adst);
    float denom = 1.f;
    float acc = h2[(size_t)i * DH + lane];

    for (int j0 = 0; j0 < deg; j0 += 4) {
        int   s[4]; float e[4];
#pragma unroll
        for (int k = 0; k < 4; ++k) {
            int jj = j0 + k;
            int jv = (jj < deg) ? jj : j0;
            s[k] = (jv < 64) ? __shfl(myidx, jv, 64) : col_idx[jb + jv];
            e[k] = (jj < deg) ? lrelu(a_s2[s[k]] + adst) : -1e30f;
        }
        float r[4];
#pragma unroll
        for (int k = 0; k < 4; ++k) r[k] = h2[(size_t)s[k] * DH + lane];

        float bm = fmaxf(fmaxf(e[0], e[1]), fmaxf(e[2], e[3]));
        float mn = fmaxf(m, bm);
        float sc = __expf(m - mn);
        float w0 = __expf(e[0] - mn), w1 = __expf(e[1] - mn);
        float w2 = __expf(e[2] - mn), w3 = __expf(e[3] - mn);
        denom = denom * sc + ((w0 + w1) + (w2 + w3));
        acc   = acc   * sc + (w0 * r[0] + w1 * r[1]) + (w2 * r[2] + w3 * r[3]);
        m = mn;
    }

    float val = acc / denom + ldf(b2, lane, f32);
    size_t oi = (size_t)i * DH + lane;
    if (f32) ((float*)out)[oi] = val;
    else     ((__hip_bfloat16*)out)[oi] = __float2bfloat16(val);
}

// ---------------- launch ----------------

static void* g_scratch = nullptr;   // fallback only; allocated on first (non-captured) call

extern "C" void kernel_launch(void* const* d_in, const int* in_sizes, int n_in,
                              void* d_out, int out_size, void* d_ws, size_t ws_size,
                              hipStream_t stream) {
    const unsigned short* x   = (const unsigned short*)d_in[0];
    const int*            ei  = (const int*)d_in[1];
    const unsigned short* W1  = (const unsigned short*)d_in[2];
    const unsigned short* as1 = (const unsigned short*)d_in[3];
    const unsigned short* ad1 = (const unsigned short*)d_in[4];
    const unsigned short* b1  = (const unsigned short*)d_in[5];
    const unsigned short* W2  = (const unsigned short*)d_in[6];
    const unsigned short* as2 = (const unsigned short*)d_in[7];
    const unsigned short* ad2 = (const unsigned short*)d_in[8];
    const unsigned short* b2  = (const unsigned short*)d_in[9];

    const int* srcv = ei;
    const int* dstv = ei + NE;

    const size_t need = (16 + (size_t)NN * DH * 2 + (size_t)NN * H1N * 2
                         + (size_t)NN * 3 + 1 + (size_t)NE) * 4;
    void* wsbase = d_ws;
    if (ws_size < need) {
        if (g_scratch == nullptr) hipMalloc(&g_scratch, need);
        wsbase = g_scratch;
    }

    int*   flag = (int*)wsbase;              // 16 ints
    float* h1   = (float*)wsbase + 16;       // NN*64 (reused as h2)
    float* hmid = h1   + (size_t)NN * DH;    // NN*64
    float* a_s1 = hmid + (size_t)NN * DH;    // NN*8
    float* a_d1 = a_s1 + (size_t)NN * H1N;   // NN*8
    int* counts  = (int*)(a_d1 + (size_t)NN * H1N);  // NN
    int* row_ptr = counts  + NN;             // NN+1
    int* cursor  = row_ptr + (NN + 1);       // NN
    int* col_idx = cursor  + NN;             // NE
    float* h2   = h1;                        // alias: h1 dead after agg1
    float* a_s2 = a_s1;                      // alias
    float* a_d2 = a_d1;                      // alias

    hipMemsetAsync(counts, 0, NN * sizeof(int), stream);
    gat_detect<<<1, 256, 0, stream>>>(W1, flag);

    int eb = (NE + 255) / 256;
    gat_degree <<<eb, 256, 0, stream>>>(dstv, counts);
    gat_scan   <<<1, 256, 0, stream>>>(counts, row_ptr, cursor);
    gat_scatter<<<eb, 256, 0, stream>>>(srcv, dstv, cursor, col_idx);

    gat_gemm1<<<1024, 256, 0, stream>>>(x, W1, as1, ad1, flag, h1, a_s1, a_d1, 0, 0);
    gat_gemm1<<<1024, 256, 0, stream>>>(x, W1, as1, ad1, flag, h1, a_s1, a_d1, 256, 1);

    int nb = (NN * 64 + 255) / 256;   // one wave per node
    gat_agg1<<<nb, 256, 0, stream>>>(row_ptr, col_idx, a_s1, a_d1, h1, b1, flag, hmid);

    gat_gemm2<<<512, 256, 0, stream>>>(hmid, W2, as2, ad2, flag, h2, a_s2, a_d2);

    gat_agg2<<<nb, 256, 0, stream>>>(row_ptr, col_idx, a_s2, a_d2, h2, b2, flag, d_out);
}